// Round 3
// baseline (312.091 us; speedup 1.0000x reference)
//
#include <hip/hip_runtime.h>

// pos[b,n,j] = sum_i rel[b,n,i] * basis[b,i,j]
__global__ void pos_kernel(const float* __restrict__ rel,
                           const float* __restrict__ basis,
                           float* __restrict__ pos,
                           int BN, int N) {
    int idx = blockIdx.x * blockDim.x + threadIdx.x;
    if (idx >= BN) return;
    int b = idx / N;
    const float* bm = basis + b * 9;
    float x = rel[idx * 3 + 0], y = rel[idx * 3 + 1], z = rel[idx * 3 + 2];
    pos[idx * 3 + 0] = x * bm[0] + y * bm[3] + z * bm[6];
    pos[idx * 3 + 1] = x * bm[1] + y * bm[4] + z * bm[7];
    pos[idx * 3 + 2] = x * bm[2] + y * bm[5] + z * bm[8];
}

// per-batch 3x3 inverse (adjugate / det)
__global__ void inv_kernel(const float* __restrict__ basis,
                           float* __restrict__ recip, int B) {
    int b = blockIdx.x * blockDim.x + threadIdx.x;
    if (b >= B) return;
    const float* m = basis + b * 9;
    float a00 = m[0], a01 = m[1], a02 = m[2];
    float a10 = m[3], a11 = m[4], a12 = m[5];
    float a20 = m[6], a21 = m[7], a22 = m[8];
    float c00 = a11 * a22 - a12 * a21;
    float c01 = -(a10 * a22 - a12 * a20);
    float c02 = a10 * a21 - a11 * a20;
    float det = a00 * c00 + a01 * c01 + a02 * c02;
    float id = 1.0f / det;
    float* r = recip + b * 9;
    r[0] = c00 * id;
    r[1] = (a02 * a21 - a01 * a22) * id;
    r[2] = (a01 * a12 - a02 * a11) * id;
    r[3] = c01 * id;
    r[4] = (a00 * a22 - a02 * a20) * id;
    r[5] = (a02 * a10 - a00 * a12) * id;
    r[6] = c02 * id;
    r[7] = (a01 * a20 - a00 * a21) * id;
    r[8] = (a00 * a11 - a01 * a10) * id;
}

// per-edge: disp = pos[b,dst] - pos[b,src] + shift; scatter prefactor*disp onto src
__global__ void edge_kernel(const float* __restrict__ pos,
                            const float* __restrict__ shifts,
                            const int* __restrict__ src,
                            const int* __restrict__ dst,
                            const int* __restrict__ bch,
                            float* __restrict__ cart,
                            int E, int N) {
    int e = blockIdx.x * blockDim.x + threadIdx.x;
    if (e >= E) return;
    int b = bch[e], s = src[e], d = dst[e];
    int base = b * N;
    const float* pd = pos + (size_t)(base + d) * 3;
    const float* ps = pos + (size_t)(base + s) * 3;
    float dx = pd[0] - ps[0] + shifts[(size_t)e * 3 + 0];
    float dy = pd[1] - ps[1] + shifts[(size_t)e * 3 + 1];
    float dz = pd[2] - ps[2] + shifts[(size_t)e * 3 + 2];
    float r = sqrtf(dx * dx + dy * dy + dz * dz);
    float pref = 2.0f * (r - 3.0f) / (r + 1e-8f);  // STRENGTH = 1.0, CUTOFF = 3.0
    float* c = cart + (size_t)(base + s) * 3;
    atomicAdd(&c[0], pref * dx);
    atomicAdd(&c[1], pref * dy);
    atomicAdd(&c[2], pref * dz);
}

// out[b,n,j] = raw[b,n,j] + sum_i cart[b,n,i] * recip[b,i,j]
__global__ void out_kernel(const float* __restrict__ cart,
                           const float* __restrict__ recip,
                           const float* __restrict__ raw,
                           float* __restrict__ out,
                           int BN, int N) {
    int idx = blockIdx.x * blockDim.x + threadIdx.x;
    if (idx >= BN) return;
    int b = idx / N;
    const float* rm = recip + b * 9;
    float x = cart[idx * 3 + 0], y = cart[idx * 3 + 1], z = cart[idx * 3 + 2];
    out[idx * 3 + 0] = raw[idx * 3 + 0] + x * rm[0] + y * rm[3] + z * rm[6];
    out[idx * 3 + 1] = raw[idx * 3 + 1] + x * rm[1] + y * rm[4] + z * rm[7];
    out[idx * 3 + 2] = raw[idx * 3 + 2] + x * rm[2] + y * rm[5] + z * rm[8];
}

extern "C" void kernel_launch(void* const* d_in, const int* in_sizes, int n_in,
                              void* d_out, int out_size, void* d_ws, size_t ws_size,
                              hipStream_t stream) {
    const float* rel    = (const float*)d_in[0];
    const float* basis  = (const float*)d_in[1];
    const float* shifts = (const float*)d_in[2];
    const float* raw    = (const float*)d_in[3];
    const int*   src    = (const int*)d_in[4];
    const int*   dst    = (const int*)d_in[5];
    const int*   bch    = (const int*)d_in[6];

    int B  = in_sizes[1] / 9;
    int BN = in_sizes[0] / 3;
    int N  = BN / B;
    int E  = in_sizes[4];

    float* pos   = (float*)d_ws;
    float* cart  = pos + (size_t)BN * 3;
    float* recip = cart + (size_t)BN * 3;

    // zero the scatter accumulator every call (ws is poisoned once, never restored)
    hipMemsetAsync(cart, 0, (size_t)BN * 3 * sizeof(float), stream);

    pos_kernel<<<(BN + 255) / 256, 256, 0, stream>>>(rel, basis, pos, BN, N);
    inv_kernel<<<1, 64, 0, stream>>>(basis, recip, B);
    edge_kernel<<<(E + 255) / 256, 256, 0, stream>>>(pos, shifts, src, dst, bch, cart, E, N);
    out_kernel<<<(BN + 255) / 256, 256, 0, stream>>>(cart, recip, raw, (float*)d_out, BN, N);
}